// Round 7
// baseline (11995.888 us; speedup 1.0000x reference)
//
#include <hip/hip_runtime.h>
#include <math.h>

#define D 256
#define NH 4
#define HDIM 64
#define FFD 2048
#define NL 3
#define VOC 30000
#define BPTT 20
#define BATCH 64
#define NMAX (BPTT*BATCH)   /* 1280 */
#define NCOLT 118           /* ceil(VOC/256) */
#define TROWS 64
#define NWG 256
#define NTHR 512

struct Params {
  const float* image_feats; const int* target; const float* emb_table;
  const float* W_g2e; const float* b_g2e;
  const float* W_out; const float* b_out;
  const float* Wqkv; const float* bqkv;
  const float* Wo;   const float* bo;
  const float* W1;   const float* b1;
  const float* W2;   const float* b2;
  const float* g1;   const float* be1;
  const float* g2;   const float* be2;
  float* out_probs; float* out_words; float* out_eos;
  float* embeds; float* xcur; float* xln1; float* qkvb0; float* qkvb;
  float* pp; float* fp; float* logits;
  float* pm; float* pd; float* pv; float* gS;
  int* pi; int* maskS;
  unsigned* flags;
};

// ---- device-coherent (cross-XCD) access via LLC ----
__device__ __forceinline__ float cld(const float* p) {
  return __hip_atomic_load(p, __ATOMIC_RELAXED, __HIP_MEMORY_SCOPE_AGENT);
}
__device__ __forceinline__ void cst(float* p, float v) {
  __hip_atomic_store(p, v, __ATOMIC_RELAXED, __HIP_MEMORY_SCOPE_AGENT);
}
__device__ __forceinline__ int cldi(const int* p) {
  return __hip_atomic_load(p, __ATOMIC_RELAXED, __HIP_MEMORY_SCOPE_AGENT);
}
__device__ __forceinline__ void csti(int* p, int v) {
  __hip_atomic_store(p, v, __ATOMIC_RELAXED, __HIP_MEMORY_SCOPE_AGENT);
}
// 8-byte coherent pair accesses (8B-aligned addresses only)
__device__ __forceinline__ float2 cld2(const float* p) {
  unsigned long long u = __hip_atomic_load((const unsigned long long*)p,
                                           __ATOMIC_RELAXED, __HIP_MEMORY_SCOPE_AGENT);
  union { unsigned long long u; float2 f; } x; x.u = u; return x.f;
}
__device__ __forceinline__ void cst2(float* p, float a, float b) {
  union { unsigned long long u; float f[2]; } x; x.f[0] = a; x.f[1] = b;
  __hip_atomic_store((unsigned long long*)p, x.u,
                     __ATOMIC_RELAXED, __HIP_MEMORY_SCOPE_AGENT);
}

__device__ __forceinline__ float wredsum(float s) {
  for (int off = 32; off; off >>= 1) s += __shfl_down(s, off);
  return __shfl(s, 0);
}
__device__ __forceinline__ float wredmax(float m) {
  for (int off = 32; off; off >>= 1) m = fmaxf(m, __shfl_down(m, off));
  return __shfl(m, 0);
}

// ---- broadcast grid barrier (r6-verified) ----
__device__ __forceinline__ void gbar(unsigned* flags, unsigned epoch) {
  unsigned* rel = flags + NWG*32;
  asm volatile("s_waitcnt vmcnt(0) lgkmcnt(0)" ::: "memory");
  __syncthreads();
  if (blockIdx.x == 0) {
    int ok;
    do {
      int mine = 1;
      if (threadIdx.x > 0 && threadIdx.x < NWG)
        mine = ((int)(__hip_atomic_load(&flags[(unsigned)threadIdx.x * 32u],
                      __ATOMIC_RELAXED, __HIP_MEMORY_SCOPE_AGENT) - epoch) >= 0);
      ok = __syncthreads_and(mine);
      if (!ok) __builtin_amdgcn_s_sleep(1);
    } while (!ok);
    if (threadIdx.x == 0)
      __hip_atomic_store(rel, epoch, __ATOMIC_RELAXED, __HIP_MEMORY_SCOPE_AGENT);
  } else {
    if (threadIdx.x == 0) {
      __hip_atomic_store(&flags[(unsigned)blockIdx.x * 32u], epoch,
                         __ATOMIC_RELAXED, __HIP_MEMORY_SCOPE_AGENT);
      while ((int)(__hip_atomic_load(rel, __ATOMIC_RELAXED,
                   __HIP_MEMORY_SCOPE_AGENT) - epoch) < 0)
        __builtin_amdgcn_s_sleep(2);
    }
    __syncthreads();
  }
  asm volatile("" ::: "memory");
}

// ---- stage 64x256 rows (coherent src, 8B loads) ----
__device__ __forceinline__ void stage64(float (*As)[D], const float* src, long row0) {
  for (int idx = threadIdx.x; idx < TROWS*D/2; idx += NTHR) {
    int r = idx >> 7, c2 = (idx & 127)*2;
    float2 v = cld2(src + (row0 + r)*(long)D + c2);
    As[r][c2] = v.x; As[r][c2+1] = v.y;
  }
}

// ---- stage 64 rows with fused residual+partials sum and LayerNorm (8B) ----
// wave w handles rows w*8+j (j<8); per-row reduction order identical to r6.
__device__ __forceinline__ void stageLN(float (*As)[D], const float* resid, long row0,
    const float* parts, int nparts, long pstride,
    const float* bias, const float* g, const float* be, float* wr) {
  const int tid = threadIdx.x;
  for (int idx = tid; idx < TROWS*D/2; idx += NTHR) {
    int r = idx >> 7, c2 = (idx & 127)*2;
    long row = row0 + r;
    float2 v = cld2(resid + row*D + c2);
    float vx = v.x + bias[c2], vy = v.y + bias[c2+1];
    for (int q = 0; q < nparts; ++q) {
      float2 pv = cld2(parts + (long)q*pstride + row*D + c2);
      vx += pv.x; vy += pv.y;
    }
    As[r][c2] = vx; As[r][c2+1] = vy;
  }
  __syncthreads();
  const int lane = tid & 63, w = tid >> 6;
#pragma unroll
  for (int j = 0; j < 8; ++j) {
    int r = w*8 + j;
    float4 x = *(float4*)&As[r][lane*4];
    float mu = wredsum(x.x+x.y+x.z+x.w) * (1.f/D);
    float dx = x.x-mu, dy = x.y-mu, dz = x.z-mu, dw = x.w-mu;
    float var = wredsum(dx*dx+dy*dy+dz*dz+dw*dw) * (1.f/D);
    float inv = 1.f/sqrtf(var + 1e-5f);
    float4 gg = *(const float4*)&g[lane*4];
    float4 bb = *(const float4*)&be[lane*4];
    float4 o;
    o.x = dx*inv*gg.x + bb.x; o.y = dy*inv*gg.y + bb.y;
    o.z = dz*inv*gg.z + bb.z; o.w = dw*inv*gg.w + bb.w;
    *(float4*)&As[r][lane*4] = o;
    if (wr) {
      long row = row0 + r;
      cst2(&wr[row*D + lane*4],     o.x, o.y);
      cst2(&wr[row*D + lane*4 + 2], o.z, o.w);
    }
  }
  __syncthreads();
}

// ---- 64x256 @ 256xM tile, 512 threads: wave w rows w*8+j (j<8), lane cols lane*4..+3
// 8 rows/thread: per inner round 128 FMA vs 4 W-loads -> VALU/L1 balanced.
__device__ __forceinline__ void mm64(const float (*As)[D], const float* __restrict__ Wp,
                                     long M, float acc[8][4]) {
  const int r0 = (threadIdx.x >> 6) * 8;
  for (int kk = 0; kk < D; kk += 4) {
    float w[4][4];
#pragma unroll
    for (int q = 0; q < 4; ++q)
      *(float4*)w[q] = *(const float4*)(Wp + (long)(kk+q)*M);
#pragma unroll
    for (int j = 0; j < 8; ++j) {
      float a[4];
      *(float4*)a = *(const float4*)&As[r0+j][kk];
#pragma unroll
      for (int c = 0; c < 4; ++c)
#pragma unroll
        for (int q = 0; q < 4; ++q)
          acc[j][c] += a[q]*w[q][c];
    }
  }
}

__global__ __launch_bounds__(NTHR, 2) void mega(Params p) {
  extern __shared__ char smraw[];
  float (*As)[D] = (float(*)[D])smraw;                 // 64KB
  float* sm = (float*)smraw;
  const int tid = threadIdx.x, wgid = blockIdx.x;
  const int lane = tid & 63, wave = tid >> 6;
  unsigned ep = 0;
  unsigned* flags = p.flags;

  // ================= init: img embed (blocks 0..63) =================
  if (wgid < BATCH) {
    int b = wgid;
    for (int idx = tid; idx < 2048; idx += NTHR) sm[idx] = p.image_feats[b*2048 + idx];
    __syncthreads();
    if (tid < D) {
      float acc = 0.f;
      for (int k = 0; k < 2048; k += 4) {
        float4 xv = *(const float4*)&sm[k];
        acc += xv.x * p.W_g2e[(k+0)*D + tid];
        acc += xv.y * p.W_g2e[(k+1)*D + tid];
        acc += xv.z * p.W_g2e[(k+2)*D + tid];
        acc += xv.w * p.W_g2e[(k+3)*D + tid];
      }
      cst(&p.embeds[(long)b*D + tid], acc + p.b_g2e[tid]);
    }
  }
  gbar(flags, ++ep);

  // ================= decode loop =================
  for (int i = 0; i < BPTT; ++i) {
    const int S = i + 1;

    // ---- PH1: A0 new-row qkv (blocks 118..120, 1 row-tile x 3 col-parts)
    //          || H(i-1): out_probs update (blocks 0..117) ----
    if (wgid >= NCOLT && wgid < NCOLT + 3) {
      int cp = wgid - NCOLT;
      long row0 = (long)i*BATCH;
      stage64(As, p.embeds, row0);
      __syncthreads();
      float acc[8][4] = {};
      int col = cp*256 + lane*4;
      mm64(As, p.Wqkv + col, 3*D, acc);
      float bv[4]; *(float4*)bv = *(const float4*)(p.bqkv + col);
      const int r0 = wave*8;
      for (int j = 0; j < 8; ++j) {
        long row = row0 + r0 + j;
        cst2(&p.qkvb0[row*768 + col],     acc[j][0] + bv[0], acc[j][1] + bv[1]);
        cst2(&p.qkvb0[row*768 + col + 2], acc[j][2] + bv[2], acc[j][3] + bv[3]);
      }
    } else if (wgid < NCOLT && i > 0) {
      float* gm = sm; float* ss = sm + 64; int* mk = (int*)(sm + 128);
      if (tid < 64) {
        gm[tid] = cld(&p.gS[tid*2]); ss[tid] = cld(&p.gS[tid*2+1]);
        mk[tid] = cldi(&p.maskS[tid]);
      }
      __syncthreads();
      int cbase = wgid*256;
      for (int idx = tid; idx < BATCH*128; idx += NTHR) {
        int b = idx >> 7, c = cbase + (idx & 127)*2;
        if (c < VOC && (i-1 == 0 || mk[b])) {
          float2 l = cld2(&p.logits[(long)b*VOC + c]);
          float pr0 = expf(l.x - gm[b]) / ss[b];
          float pr1 = expf(l.y - gm[b]) / ss[b];
          float* op = &p.out_probs[(long)b*VOC + c];
          if (i-1 == 0) { op[0] = pr0; op[1] = pr1; }
          else { op[0] = fmaxf(op[0], pr0); op[1] = fmaxf(op[1], pr1); }
        }
      }
    }
    gbar(flags, ++ep);

    for (int l = 0; l < NL; ++l) {
      // ---- B: attention + per-head proj partial (block = (b,h)) ----
      {
        const float* src = (l == 0) ? p.qkvb0 : p.qkvb;
        float* qs = sm; float* ks = sm + 1280; float* vs = sm + 2560;
        float* ps = sm + 3840;
        int b = wgid & 63, h = wgid >> 6;
        for (int idx = tid; idx < S*32; idx += NTHR) {
          int s = idx >> 5, d2 = (idx & 31)*2;
          long base = (long)(s*BATCH + b)*768 + h*HDIM + d2;
          float2 qv = cld2(&src[base]);
          float2 kv = cld2(&src[base + D]);
          float2 vv = cld2(&src[base + 2*D]);
          qs[s*HDIM+d2] = qv.x; qs[s*HDIM+d2+1] = qv.y;
          ks[s*HDIM+d2] = kv.x; ks[s*HDIM+d2+1] = kv.y;
          vs[s*HDIM+d2] = vv.x; vs[s*HDIM+d2+1] = vv.y;
        }
        __syncthreads();
        const float* Wo2 = p.Wo + (long)l*D*D + (long)h*HDIM*D;
        if (l < NL-1) {
          for (int idx = tid; idx < S*S; idx += NTHR) {
            int si = idx / S, ti = idx - si*S;
            float a = 0.f;
#pragma unroll 8
            for (int k = 0; k < HDIM; ++k) a += qs[si*HDIM+k]*ks[ti*HDIM+k];
            ps[si*(BPTT+1)+ti] = a * 0.125f;
          }
          __syncthreads();
          for (int r = wave; r < S; r += 8) {
            float v = (lane < S) ? ps[r*(BPTT+1)+lane] : -1e30f;
            float m = wredmax(v);
            float e = (lane < S) ? expf(v - m) : 0.f;
            float ssum = wredsum(e);
            if (lane < S) ps[r*(BPTT+1)+lane] = e / ssum;
          }
          __syncthreads();
          for (int idx = tid; idx < S*HDIM; idx += NTHR) {
            int s = idx >> 6, d = idx & 63;
            float a = 0.f;
            for (int t2 = 0; t2 < S; ++t2) a += ps[s*(BPTT+1)+t2]*vs[t2*HDIM+d];
            qs[idx] = a;   // o overwrites q (q dead after scores)
          }
          __syncthreads();
          int c0 = lane*4;
          float acc[3][4] = {};
          for (int k = 0; k < HDIM; ++k) {
            float4 w = *(const float4*)&Wo2[(long)k*D + c0];
#pragma unroll
            for (int jj = 0; jj < 3; ++jj) {
              int r = wave + 8*jj;
              float a = (r < S) ? qs[r*HDIM + k] : 0.f;
              acc[jj][0]+=a*w.x; acc[jj][1]+=a*w.y; acc[jj][2]+=a*w.z; acc[jj][3]+=a*w.w;
            }
          }
          for (int jj = 0; jj < 3; ++jj) {
            int r = wave + 8*jj;
            if (r < S) {
              long row = (long)r*BATCH + b;
              cst2(&p.pp[((long)h*NMAX + row)*D + c0],     acc[jj][0], acc[jj][1]);
              cst2(&p.pp[((long)h*NMAX + row)*D + c0 + 2], acc[jj][2], acc[jj][3]);
            }
          }
        } else {
          // l==2: only the last q-row (s=i) is ever consumed
          if (tid < S) {
            float a = 0.f;
            for (int k = 0; k < HDIM; ++k) a += qs[i*HDIM+k]*ks[tid*HDIM+k];
            ps[tid] = a * 0.125f;
          }
          __syncthreads();
          if (wave == 0) {
            float v = (lane < S) ? ps[lane] : -1e30f;
            float m = wredmax(v);
            float e = (lane < S) ? expf(v - m) : 0.f;
            float ssum = wredsum(e);
            if (lane < S) ps[lane] = e / ssum;
          }
          __syncthreads();
          if (tid < HDIM) {
            float a = 0.f;
            for (int t2 = 0; t2 < S; ++t2) a += ps[t2]*vs[t2*HDIM+tid];
            qs[tid] = a;
          }
          __syncthreads();
          if (tid < 128) {
            int c2 = tid*2;
            float a0 = 0.f, a1 = 0.f;
            for (int k = 0; k < HDIM; ++k) {
              a0 += qs[k]*Wo2[(long)k*D + c2];
              a1 += qs[k]*Wo2[(long)k*D + c2 + 1];
            }
            cst2(&p.pp[((long)h*NMAX + (long)i*BATCH + b)*D + c2], a0, a1);
          }
        }
      }
      gbar(flags, ++ep);

      // ---- D: LN1-fused stage + ff1(relu in-place) + ff2 partial ----
      //      64-row tiles: nrt = S (l<2) or 1 (l==2); y = wgid&7 XCD-stable.
      {
        const float* resid = (l == 0) ? p.embeds : p.xcur;
        const float* bol = p.bo + l*D;
        const float* g1l = p.g1 + l*D; const float* be1l = p.be1 + l*D;
        const float* W1l = p.W1 + (long)l*D*FFD;
        const float* b1l = p.b1 + (long)l*FFD;
        const float* W2l = p.W2 + (long)l*FFD*D;
        const int y = wgid & 7, slot = wgid >> 3;
        const int nrt = (l == NL-1) ? 1 : S;
        const long rbase = (l == NL-1) ? (long)i*BATCH : 0;
        for (int tt = slot; tt < nrt; tt += 32) {
          long row0 = rbase + (long)tt*TROWS;
          stageLN(As, resid, row0, p.pp, 4, (long)NMAX*D, bol, g1l, be1l,
                  (y == 0) ? p.xln1 : nullptr);
          float acc1[8][4] = {};
          int fcol = y*256 + lane*4;
          mm64(As, W1l + fcol, FFD, acc1);
          float bv[4]; *(float4*)bv = *(const float4*)(b1l + fcol);
          const int r0 = wave*8;
          __syncthreads();   // all ff1 reads of As complete
          for (int j = 0; j < 8; ++j)
            for (int c = 0; c < 4; ++c)
              As[r0+j][lane*4+c] = fmaxf(acc1[j][c] + bv[c], 0.f);
          __syncthreads();   // ff values visible
          float acc2[8][4] = {};
          mm64(As, W2l + (long)(y*256)*D + lane*4, D, acc2);
          for (int j = 0; j < 8; ++j) {
            long row = row0 + r0 + j;
            cst2(&p.fp[((long)y*NMAX + row)*D + lane*4],     acc2[j][0], acc2[j][1]);
            cst2(&p.fp[((long)y*NMAX + row)*D + lane*4 + 2], acc2[j][2], acc2[j][3]);
          }
          __syncthreads();
        }
      }
      gbar(flags, ++ep);

      // ---- AE (l<2): LN2-fused stage + qkv for layer l+1 ; tiles = 3S ----
      if (l + 1 < NL) {
        const float* b2l = p.b2 + l*D;
        const float* g2l = p.g2 + l*D; const float* be2l = p.be2 + l*D;
        const float* Wl = p.Wqkv + (long)(l+1)*D*768;
        const float* bl = p.bqkv + (long)(l+1)*768;
        for (int t = wgid; t < 3*S; t += NWG) {
          int tt = t % S, cp = t / S;
          long row0 = (long)tt*TROWS;
          stageLN(As, p.xln1, row0, p.fp, 8, (long)NMAX*D, b2l, g2l, be2l,
                  (cp == 0) ? p.xcur : nullptr);
          float acc[8][4] = {};
          int col = cp*256 + lane*4;
          mm64(As, Wl + col, 768, acc);
          float bv[4]; *(float4*)bv = *(const float4*)(bl + col);
          const int r0 = wave*8;
          for (int j = 0; j < 8; ++j) {
            long row = row0 + r0 + j;
            cst2(&p.qkvb[row*768 + col],     acc[j][0] + bv[0], acc[j][1] + bv[1]);
            cst2(&p.qkvb[row*768 + col + 2], acc[j][2] + bv[2], acc[j][3] + bv[3]);
          }
          __syncthreads();
        }
        gbar(flags, ++ep);
      }
    } // layers

    // ---- F: LN2-fused stage + logits, 1 row-tile x 118 col-tiles ----
    {
      const float* b2l = p.b2 + (NL-1)*D;
      const float* g2l = p.g2 + (NL-1)*D; const float* be2l = p.be2 + (NL-1)*D;
      const int colt = wgid;   // block<->colt fixed across steps (XCD-stable)
      if (colt < NCOLT) {
        long row0 = (long)i*BATCH;
        stageLN(As, p.xln1, row0, p.fp, 8, (long)NMAX*D, b2l, g2l, be2l, nullptr);
        int col = colt*256 + lane*4;
        int colL = col > VOC-4 ? VOC-4 : col;
        float acc[8][4] = {};
        mm64(As, p.W_out + colL, VOC, acc);
        float bv[4]; *(float4*)bv = *(const float4*)(p.b_out + colL);
        bool valid = (col < VOC);
        const int r0 = wave*8;
        for (int j = 0; j < 8; ++j) {
          int b = r0 + j;
          float v4[4]; float lm = -1e30f;
          for (int c = 0; c < 4; ++c) v4[c] = acc[j][c] + bv[c];
          if (valid) {
            cst2(&p.logits[(long)b*VOC + col],     v4[0], v4[1]);
            cst2(&p.logits[(long)b*VOC + col + 2], v4[2], v4[3]);
            for (int c = 0; c < 4; ++c) lm = fmaxf(lm, v4[c]);
          }
          float m = wredmax(lm);
          float ls = 0.f;
          if (valid) for (int c = 0; c < 4; ++c) ls += expf(v4[c] - m);
          for (int off = 32; off; off >>= 1) ls += __shfl_down(ls, off);
          float av = -1e30f; int ai = VOC;
          if (valid) for (int c = 0; c < 4; ++c) if (v4[c] > av) { av = v4[c]; ai = col + c; }
          for (int off = 32; off; off >>= 1) {
            float av2 = __shfl_down(av, off); int ai2 = __shfl_down(ai, off);
            if (av2 > av || (av2 == av && ai2 < ai)) { av = av2; ai = ai2; }
          }
          if (lane == 0) {
            int pidx = colt*64 + b;
            cst(&p.pm[pidx], m); cst(&p.pd[pidx], ls);
            cst(&p.pv[pidx], av); csti(&p.pi[pidx], ai);
          }
        }
      }
    }
    gbar(flags, ++ep);

    // ---- G: per-b merge; outputs + next embed ----
    if (wgid < BATCH) {
      int b = wgid;
      float* Lm = sm; float* Ld = sm + 128; float* Lv = sm + 256;
      int* Li = (int*)(sm + 384); int* Lei = Li + 128;
      if (tid < NCOLT) {
        Lm[tid] = cld(&p.pm[tid*64 + b]);
        Ld[tid] = cld(&p.pd[tid*64 + b]);
        Lv[tid] = cld(&p.pv[tid*64 + b]);
        Li[tid] = cldi(&p.pi[tid*64 + b]);
      }
      __syncthreads();
      if (tid == 0) {
        float gmax = -1e30f;
        for (int t2 = 0; t2 < NCOLT; ++t2) gmax = fmaxf(gmax, Lm[t2]);
        float Ssum = 0.f;
        for (int t2 = 0; t2 < NCOLT; ++t2) Ssum += Ld[t2] * expf(Lm[t2] - gmax);
        float bvv = -1e30f; int bi = VOC;
        for (int t2 = 0; t2 < NCOLT; ++t2)
          if (Lv[t2] > bvv || (Lv[t2] == bvv && Li[t2] < bi)) { bvv = Lv[t2]; bi = Li[t2]; }
        int run = 1;
        for (int j = 1; j <= i; ++j) if (p.target[b*BPTT + j] == 2) run = 0;
        float p2 = expf(cld(&p.logits[(long)b*VOC + 2]) - gmax) / Ssum;
        p.out_eos[b*BPTT + i] = p2;
        p.out_words[b*BPTT + i] = run ? (float)bi : 0.f;
        cst(&p.gS[b*2], gmax);
        cst(&p.gS[b*2+1], Ssum);
        csti(&p.maskS[b], run);
        Lei[0] = bi;
      }
      __syncthreads();
      if (i + 1 < BPTT && tid < 128) {
        int ei = Lei[0];
        int c2 = tid*2;
        cst2(&p.embeds[((long)(i+1)*BATCH + b)*D + c2],
             p.emb_table[(long)ei*D + c2], p.emb_table[(long)ei*D + c2 + 1]);
      }
    }
    gbar(flags, ++ep);
  } // steps

  // ---- final H: out_probs update for step 19 ----
  if (wgid < NCOLT) {
    float* gm = sm; float* ss = sm + 64; int* mk = (int*)(sm + 128);
    if (tid < 64) {
      gm[tid] = cld(&p.gS[tid*2]); ss[tid] = cld(&p.gS[tid*2+1]);
      mk[tid] = cldi(&p.maskS[tid]);
    }
    __syncthreads();
    int cbase = wgid*256;
    for (int idx = tid; idx < BATCH*128; idx += NTHR) {
      int b = idx >> 7, c = cbase + (idx & 127)*2;
      if (c < VOC && mk[b]) {
        float2 l = cld2(&p.logits[(long)b*VOC + c]);
        float pr0 = expf(l.x - gm[b]) / ss[b];
        float pr1 = expf(l.y - gm[b]) / ss[b];
        float* op = &p.out_probs[(long)b*VOC + c];
        op[0] = fmaxf(op[0], pr0);
        op[1] = fmaxf(op[1], pr1);
      }
    }
  }
}

// ---------------- host ----------------
extern "C" void kernel_launch(void* const* d_in, const int* in_sizes, int n_in,
                              void* d_out, int out_size, void* d_ws, size_t ws_size,
                              hipStream_t stream) {
  Params P;
  P.image_feats = (const float*)d_in[0];
  P.target      = (const int*)  d_in[1];
  P.emb_table   = (const float*)d_in[2];
  P.W_g2e       = (const float*)d_in[3];
  P.b_g2e       = (const float*)d_in[4];
  P.W_out       = (const float*)d_in[5];
  P.b_out       = (const float*)d_in[6];
  P.Wqkv        = (const float*)d_in[7];
  P.bqkv        = (const float*)d_in[8];
  P.Wo          = (const float*)d_in[9];
  P.bo          = (const float*)d_in[10];
  P.W1          = (const float*)d_in[11];
  P.b1          = (const float*)d_in[12];
  P.W2          = (const float*)d_in[13];
  P.b2          = (const float*)d_in[14];
  P.g1          = (const float*)d_in[15];
  P.be1         = (const float*)d_in[16];
  P.g2          = (const float*)d_in[17];
  P.be2         = (const float*)d_in[18];

  float* out_probs = (float*)d_out;
  P.out_probs = out_probs;
  P.out_words = out_probs + (long)BATCH*VOC;
  P.out_eos   = P.out_words + BATCH*BPTT;

  char* ws = (char*)d_ws;
  P.embeds = (float*)ws;  ws += sizeof(float)*(long)NMAX*D;
  P.xcur   = (float*)ws;  ws += sizeof(float)*(long)NMAX*D;
  P.xln1   = (float*)ws;  ws += sizeof(float)*(long)NMAX*D;
  P.qkvb0  = (float*)ws;  ws += sizeof(float)*(long)NMAX*3*D;
  P.qkvb   = (float*)ws;  ws += sizeof(float)*(long)NMAX*3*D;
  P.pp     = (float*)ws;  ws += sizeof(float)*(long)4*NMAX*D;
  P.fp     = (float*)ws;  ws += sizeof(float)*(long)8*NMAX*D;
  P.logits = (float*)ws;  ws += sizeof(float)*(long)BATCH*VOC;
  P.pm     = (float*)ws;  ws += sizeof(float)*NCOLT*64;
  P.pd     = (float*)ws;  ws += sizeof(float)*NCOLT*64;
  P.pv     = (float*)ws;  ws += sizeof(float)*NCOLT*64;
  P.gS     = (float*)ws;  ws += sizeof(float)*128;
  P.pi     = (int*)ws;    ws += sizeof(int)*NCOLT*64;
  P.maskS  = (int*)ws;    ws += sizeof(int)*64;
  P.flags  = (unsigned*)ws; ws += sizeof(unsigned)*(NWG*32 + 32); // +release line

  static bool inited = false;
  if (!inited) {
    hipFuncSetAttribute((const void*)mega,
                        hipFuncAttributeMaxDynamicSharedMemorySize, 65536);
    inited = true;
  }

  hipMemsetAsync(P.flags, 0, sizeof(unsigned)*(NWG*32 + 32), stream);
  void* args[] = { &P };
  hipError_t err = hipLaunchCooperativeKernel((void*)mega, dim3(NWG), dim3(NTHR),
                                              args, 65536, stream);
  if (err != hipSuccess) {
    // 256 blocks x 64KB LDS = 1 block/CU on 256 CUs: co-resident by capacity.
    hipLaunchKernelGGL(mega, dim3(NWG), dim3(NTHR), 65536, stream, P);
  }
}

// Round 8
// 9234.632 us; speedup vs baseline: 1.2990x; 1.2990x over previous
//
#include <hip/hip_runtime.h>
#include <math.h>

#define D 256
#define NH 4
#define HDIM 64
#define FFD 2048
#define NL 3
#define VOC 30000
#define BPTT 20
#define BATCH 64
#define NMAX (BPTT*BATCH)   /* 1280 */
#define NCOLT 118           /* ceil(VOC/256) */
#define TROWS 32
#define NWG 256
#define NTHR 512

struct Params {
  const float* image_feats; const int* target; const float* emb_table;
  const float* W_g2e; const float* b_g2e;
  const float* W_out; const float* b_out;
  const float* Wqkv; const float* bqkv;
  const float* Wo;   const float* bo;
  const float* W1;   const float* b1;
  const float* W2;   const float* b2;
  const float* g1;   const float* be1;
  const float* g2;   const float* be2;
  float* out_probs; float* out_words; float* out_eos;
  float* embeds; float* xcur; float* xln1; float* qkvb0; float* qkvb;
  float* pp; float* fp; float* logits;
  float* pm; float* pd; float* pv; float* gS;
  int* pi; int* maskS;
  unsigned* flags;
};

// ---- device-coherent (cross-XCD) access via LLC ----
__device__ __forceinline__ float cld(const float* p) {
  return __hip_atomic_load(p, __ATOMIC_RELAXED, __HIP_MEMORY_SCOPE_AGENT);
}
__device__ __forceinline__ void cst(float* p, float v) {
  __hip_atomic_store(p, v, __ATOMIC_RELAXED, __HIP_MEMORY_SCOPE_AGENT);
}
__device__ __forceinline__ int cldi(const int* p) {
  return __hip_atomic_load(p, __ATOMIC_RELAXED, __HIP_MEMORY_SCOPE_AGENT);
}
__device__ __forceinline__ void csti(int* p, int v) {
  __hip_atomic_store(p, v, __ATOMIC_RELAXED, __HIP_MEMORY_SCOPE_AGENT);
}
// 8-byte coherent pair accesses (8B-aligned addresses only)
__device__ __forceinline__ float2 cld2(const float* p) {
  unsigned long long u = __hip_atomic_load((const unsigned long long*)p,
                                           __ATOMIC_RELAXED, __HIP_MEMORY_SCOPE_AGENT);
  union { unsigned long long u; float2 f; } x; x.u = u; return x.f;
}
__device__ __forceinline__ void cst2(float* p, float a, float b) {
  union { unsigned long long u; float f[2]; } x; x.f[0] = a; x.f[1] = b;
  __hip_atomic_store((unsigned long long*)p, x.u,
                     __ATOMIC_RELAXED, __HIP_MEMORY_SCOPE_AGENT);
}

__device__ __forceinline__ float wredsum(float s) {
  for (int off = 32; off; off >>= 1) s += __shfl_down(s, off);
  return __shfl(s, 0);
}
__device__ __forceinline__ float wredmax(float m) {
  for (int off = 32; off; off >>= 1) m = fmaxf(m, __shfl_down(m, off));
  return __shfl(m, 0);
}

// ---- broadcast grid barrier (r6-verified) ----
__device__ __forceinline__ void gbar(unsigned* flags, unsigned epoch) {
  unsigned* rel = flags + NWG*32;
  asm volatile("s_waitcnt vmcnt(0) lgkmcnt(0)" ::: "memory");
  __syncthreads();
  if (blockIdx.x == 0) {
    int ok;
    do {
      int mine = 1;
      if (threadIdx.x > 0 && threadIdx.x < NWG)
        mine = ((int)(__hip_atomic_load(&flags[(unsigned)threadIdx.x * 32u],
                      __ATOMIC_RELAXED, __HIP_MEMORY_SCOPE_AGENT) - epoch) >= 0);
      ok = __syncthreads_and(mine);
      if (!ok) __builtin_amdgcn_s_sleep(1);
    } while (!ok);
    if (threadIdx.x == 0)
      __hip_atomic_store(rel, epoch, __ATOMIC_RELAXED, __HIP_MEMORY_SCOPE_AGENT);
  } else {
    if (threadIdx.x == 0) {
      __hip_atomic_store(&flags[(unsigned)blockIdx.x * 32u], epoch,
                         __ATOMIC_RELAXED, __HIP_MEMORY_SCOPE_AGENT);
      while ((int)(__hip_atomic_load(rel, __ATOMIC_RELAXED,
                   __HIP_MEMORY_SCOPE_AGENT) - epoch) < 0)
        __builtin_amdgcn_s_sleep(2);
    }
    __syncthreads();
  }
  asm volatile("" ::: "memory");
}

// ---- stage 32x256 rows (coherent src, 8B loads) ----
__device__ __forceinline__ void stage32(float (*As)[D], const float* src, long row0) {
  for (int idx = threadIdx.x; idx < TROWS*D/2; idx += NTHR) {
    int r = idx >> 7, c2 = (idx & 127)*2;
    float2 v = cld2(src + (row0 + r)*(long)D + c2);
    As[r][c2] = v.x; As[r][c2+1] = v.y;
  }
}

// ---- stage 32 rows with fused residual+partials sum and LayerNorm (8B) ----
__device__ __forceinline__ void stageLN(float (*As)[D], const float* resid, long row0,
    const float* parts, int nparts, long pstride,
    const float* bias, const float* g, const float* be, float* wr) {
  const int tid = threadIdx.x;
  for (int idx = tid; idx < TROWS*D/2; idx += NTHR) {
    int r = idx >> 7, c2 = (idx & 127)*2;
    long row = row0 + r;
    float2 v = cld2(resid + row*D + c2);
    float vx = v.x + bias[c2], vy = v.y + bias[c2+1];
    for (int q = 0; q < nparts; ++q) {
      float2 pv = cld2(parts + (long)q*pstride + row*D + c2);
      vx += pv.x; vy += pv.y;
    }
    As[r][c2] = vx; As[r][c2+1] = vy;
  }
  __syncthreads();
  const int lane = tid & 63, w = tid >> 6;
#pragma unroll
  for (int j = 0; j < 4; ++j) {
    int r = w*4 + j;
    float4 x = *(float4*)&As[r][lane*4];
    float mu = wredsum(x.x+x.y+x.z+x.w) * (1.f/D);
    float dx = x.x-mu, dy = x.y-mu, dz = x.z-mu, dw = x.w-mu;
    float var = wredsum(dx*dx+dy*dy+dz*dz+dw*dw) * (1.f/D);
    float inv = 1.f/sqrtf(var + 1e-5f);
    float4 gg = *(const float4*)&g[lane*4];
    float4 bb = *(const float4*)&be[lane*4];
    float4 o;
    o.x = dx*inv*gg.x + bb.x; o.y = dy*inv*gg.y + bb.y;
    o.z = dz*inv*gg.z + bb.z; o.w = dw*inv*gg.w + bb.w;
    *(float4*)&As[r][lane*4] = o;
    if (wr) {
      long row = row0 + r;
      cst2(&wr[row*D + lane*4],     o.x, o.y);
      cst2(&wr[row*D + lane*4 + 2], o.z, o.w);
    }
  }
  __syncthreads();
}

// ---- staged mm: 32x256 tile @ W[256 x 256-col window].
// W is staged into LDS in 32-row chunks (ONE pass through L1/L2 per block,
// instead of 8 waves each streaming it). ds_read_b128 of Ws is stride-1 ->
// conflict-free. Per-element k-summation order is IDENTICAL to the r6
// per-lane-global version (kk ascending, q 0..3, then j, c, q).
__device__ __forceinline__ void mm32s(const float (*Xs)[D], float (*Ws)[D],
                                      const float* __restrict__ Wp, long M,
                                      float acc[4][4]) {
  const int r0 = (threadIdx.x >> 6) * 4;
  const int lane = threadIdx.x & 63;
  for (int k0 = 0; k0 < D; k0 += 32) {
    __syncthreads();
    for (int idx = threadIdx.x; idx < 32*64; idx += NTHR) {
      int r = idx >> 6, c4 = (idx & 63) * 4;
      *(float4*)&Ws[r][c4] = *(const float4*)(Wp + (long)(k0 + r)*M + c4);
    }
    __syncthreads();
    for (int kk = 0; kk < 32; kk += 4) {
      float w[4][4];
#pragma unroll
      for (int q = 0; q < 4; ++q)
        *(float4*)w[q] = *(const float4*)&Ws[kk+q][lane*4];
#pragma unroll
      for (int j = 0; j < 4; ++j) {
        float a[4];
        *(float4*)a = *(const float4*)&Xs[r0+j][k0+kk];
#pragma unroll
        for (int c = 0; c < 4; ++c)
#pragma unroll
          for (int q = 0; q < 4; ++q)
            acc[j][c] += a[q]*w[q][c];
      }
    }
  }
}

// ---- staged mm for logits: same as mm32s but with the per-4-column clamp
// the per-lane path used (colL = min(colt*256+lane*4, VOC-4)).
__device__ __forceinline__ void mm32sc(const float (*Xs)[D], float (*Ws)[D],
                                       const float* __restrict__ Wout, int colt,
                                       float acc[4][4]) {
  const int r0 = (threadIdx.x >> 6) * 4;
  const int lane = threadIdx.x & 63;
  for (int k0 = 0; k0 < D; k0 += 32) {
    __syncthreads();
    for (int idx = threadIdx.x; idx < 32*64; idx += NTHR) {
      int r = idx >> 6, c4 = (idx & 63) * 4;
      int eff = colt*256 + c4; if (eff > VOC-4) eff = VOC-4;
      *(float4*)&Ws[r][c4] = *(const float4*)(Wout + (long)(k0 + r)*VOC + eff);
    }
    __syncthreads();
    for (int kk = 0; kk < 32; kk += 4) {
      float w[4][4];
#pragma unroll
      for (int q = 0; q < 4; ++q)
        *(float4*)w[q] = *(const float4*)&Ws[kk+q][lane*4];
#pragma unroll
      for (int j = 0; j < 4; ++j) {
        float a[4];
        *(float4*)a = *(const float4*)&Xs[r0+j][k0+kk];
#pragma unroll
        for (int c = 0; c < 4; ++c)
#pragma unroll
          for (int q = 0; q < 4; ++q)
            acc[j][c] += a[q]*w[q][c];
      }
    }
  }
}

__global__ __launch_bounds__(NTHR, 2) void mega(Params p) {
  extern __shared__ char smraw[];
  float (*As)[D] = (float(*)[D])smraw;                 // 32KB
  float (*Bs)[D] = (float(*)[D])(smraw + 32768);       // 32KB (ff intermediate)
  float (*Ws)[D] = (float(*)[D])(smraw + 65536);       // 32KB (staged weights)
  float* sm = (float*)smraw;
  const int tid = threadIdx.x, wgid = blockIdx.x;
  const int lane = tid & 63, wave = tid >> 6;
  unsigned ep = 0;
  unsigned* flags = p.flags;

  // ================= init: img embed (blocks 0..63) =================
  if (wgid < BATCH) {
    int b = wgid;
    for (int idx = tid; idx < 2048; idx += NTHR) sm[idx] = p.image_feats[b*2048 + idx];
    __syncthreads();
    if (tid < D) {
      float acc = 0.f;
      for (int k = 0; k < 2048; k += 4) {
        float4 xv = *(const float4*)&sm[k];
        acc += xv.x * p.W_g2e[(k+0)*D + tid];
        acc += xv.y * p.W_g2e[(k+1)*D + tid];
        acc += xv.z * p.W_g2e[(k+2)*D + tid];
        acc += xv.w * p.W_g2e[(k+3)*D + tid];
      }
      cst(&p.embeds[(long)b*D + tid], acc + p.b_g2e[tid]);
    }
  }
  gbar(flags, ++ep);

  // ================= decode loop =================
  for (int i = 0; i < BPTT; ++i) {
    const int S = i + 1;

    // ---- PH1: A0 new-row qkv (blocks 118..123) || H(i-1): probs (0..117) ----
    if (wgid >= NCOLT && wgid < NCOLT + 6) {
      int idx = wgid - NCOLT;
      int tt = idx & 1, cp = idx >> 1;
      long row0 = (long)i*BATCH + tt*TROWS;
      stage32(As, p.embeds, row0);
      __syncthreads();
      float acc[4][4] = {};
      int col = cp*256 + lane*4;
      mm32s(As, Ws, p.Wqkv + cp*256, 3*D, acc);
      float bv[4]; *(float4*)bv = *(const float4*)(p.bqkv + col);
      const int r0 = wave*4;
      for (int j = 0; j < 4; ++j) {
        long row = row0 + r0 + j;
        cst2(&p.qkvb0[row*768 + col],     acc[j][0] + bv[0], acc[j][1] + bv[1]);
        cst2(&p.qkvb0[row*768 + col + 2], acc[j][2] + bv[2], acc[j][3] + bv[3]);
      }
    } else if (wgid < NCOLT && i > 0) {
      float* gm = sm; float* ss = sm + 64; int* mk = (int*)(sm + 128);
      if (tid < 64) {
        gm[tid] = cld(&p.gS[tid*2]); ss[tid] = cld(&p.gS[tid*2+1]);
        mk[tid] = cldi(&p.maskS[tid]);
      }
      __syncthreads();
      int cbase = wgid*256;
      for (int idx = tid; idx < BATCH*128; idx += NTHR) {
        int b = idx >> 7, c = cbase + (idx & 127)*2;
        if (c < VOC && (i-1 == 0 || mk[b])) {
          float2 l = cld2(&p.logits[(long)b*VOC + c]);
          float pr0 = expf(l.x - gm[b]) / ss[b];
          float pr1 = expf(l.y - gm[b]) / ss[b];
          float* op = &p.out_probs[(long)b*VOC + c];
          if (i-1 == 0) { op[0] = pr0; op[1] = pr1; }
          else { op[0] = fmaxf(op[0], pr0); op[1] = fmaxf(op[1], pr1); }
        }
      }
    }
    gbar(flags, ++ep);

    for (int l = 0; l < NL; ++l) {
      // ---- B: attention + per-head proj partial (block = (b,h)) ----
      {
        const float* src = (l == 0) ? p.qkvb0 : p.qkvb;
        float* qs = sm; float* ks = sm + 1280; float* vs = sm + 2560;
        float* ps = sm + 3840;
        int b = wgid & 63, h = wgid >> 6;
        for (int idx = tid; idx < S*32; idx += NTHR) {
          int s = idx >> 5, d2 = (idx & 31)*2;
          long base = (long)(s*BATCH + b)*768 + h*HDIM + d2;
          float2 qv = cld2(&src[base]);
          float2 kv = cld2(&src[base + D]);
          float2 vv = cld2(&src[base + 2*D]);
          qs[s*HDIM+d2] = qv.x; qs[s*HDIM+d2+1] = qv.y;
          ks[s*HDIM+d2] = kv.x; ks[s*HDIM+d2+1] = kv.y;
          vs[s*HDIM+d2] = vv.x; vs[s*HDIM+d2+1] = vv.y;
        }
        __syncthreads();
        const float* Wo2 = p.Wo + (long)l*D*D + (long)h*HDIM*D;
        if (l < NL-1) {
          for (int idx = tid; idx < S*S; idx += NTHR) {
            int si = idx / S, ti = idx - si*S;
            float a = 0.f;
#pragma unroll 8
            for (int k = 0; k < HDIM; ++k) a += qs[si*HDIM+k]*ks[ti*HDIM+k];
            ps[si*(BPTT+1)+ti] = a * 0.125f;
          }
          __syncthreads();
          for (int r = wave; r < S; r += 8) {
            float v = (lane < S) ? ps[r*(BPTT+1)+lane] : -1e30f;
            float m = wredmax(v);
            float e = (lane < S) ? expf(v - m) : 0.f;
            float ssum = wredsum(e);
            if (lane < S) ps[r*(BPTT+1)+lane] = e / ssum;
          }
          __syncthreads();
          for (int idx = tid; idx < S*HDIM; idx += NTHR) {
            int s = idx >> 6, d = idx & 63;
            float a = 0.f;
            for (int t2 = 0; t2 < S; ++t2) a += ps[s*(BPTT+1)+t2]*vs[t2*HDIM+d];
            qs[idx] = a;   // o overwrites q (q dead after scores)
          }
          __syncthreads();
          int c0 = lane*4;
          float acc[3][4] = {};
          for (int k = 0; k < HDIM; ++k) {
            float4 w = *(const float4*)&Wo2[(long)k*D + c0];
#pragma unroll
            for (int jj = 0; jj < 3; ++jj) {
              int r = wave + 8*jj;
              float a = (r < S) ? qs[r*HDIM + k] : 0.f;
              acc[jj][0]+=a*w.x; acc[jj][1]+=a*w.y; acc[jj][2]+=a*w.z; acc[jj][3]+=a*w.w;
            }
          }
          for (int jj = 0; jj < 3; ++jj) {
            int r = wave + 8*jj;
            if (r < S) {
              long row = (long)r*BATCH + b;
              cst2(&p.pp[((long)h*NMAX + row)*D + c0],     acc[jj][0], acc[jj][1]);
              cst2(&p.pp[((long)h*NMAX + row)*D + c0 + 2], acc[jj][2], acc[jj][3]);
            }
          }
        } else {
          // l==2: only the last q-row (s=i) is ever consumed
          if (tid < S) {
            float a = 0.f;
            for (int k = 0; k < HDIM; ++k) a += qs[i*HDIM+k]*ks[tid*HDIM+k];
            ps[tid] = a * 0.125f;
          }
          __syncthreads();
          if (wave == 0) {
            float v = (lane < S) ? ps[lane] : -1e30f;
            float m = wredmax(v);
            float e = (lane < S) ? expf(v - m) : 0.f;
            float ssum = wredsum(e);
            if (lane < S) ps[lane] = e / ssum;
          }
          __syncthreads();
          if (tid < HDIM) {
            float a = 0.f;
            for (int t2 = 0; t2 < S; ++t2) a += ps[t2]*vs[t2*HDIM+tid];
            qs[tid] = a;
          }
          __syncthreads();
          if (tid < 128) {
            int c2 = tid*2;
            float a0 = 0.f, a1 = 0.f;
            for (int k = 0; k < HDIM; ++k) {
              a0 += qs[k]*Wo2[(long)k*D + c2];
              a1 += qs[k]*Wo2[(long)k*D + c2 + 1];
            }
            cst2(&p.pp[((long)h*NMAX + (long)i*BATCH + b)*D + c2], a0, a1);
          }
        }
      }
      gbar(flags, ++ep);

      // ---- D: LN1-fused stage + ff1(relu->Bs) + ff2 partial (staged W) ----
      {
        const float* resid = (l == 0) ? p.embeds : p.xcur;
        const float* bol = p.bo + l*D;
        const float* g1l = p.g1 + l*D; const float* be1l = p.be1 + l*D;
        const float* W1l = p.W1 + (long)l*D*FFD;
        const float* b1l = p.b1 + (long)l*FFD;
        const float* W2l = p.W2 + (long)l*FFD*D;
        const int y = wgid & 7, slot = wgid >> 3;
        const int nrt = (l == NL-1) ? 2 : 2*S;
        const long rbase = (l == NL-1) ? (long)i*BATCH : 0;
        for (int tt = slot; tt < nrt; tt += 32) {
          long row0 = rbase + (long)tt*TROWS;
          stageLN(As, resid, row0, p.pp, 4, (long)NMAX*D, bol, g1l, be1l,
                  (y == 0) ? p.xln1 : nullptr);
          float acc1[4][4] = {};
          int fcol = y*256 + lane*4;
          mm32s(As, Ws, W1l + y*256, FFD, acc1);
          float bv[4]; *(float4*)bv = *(const float4*)(b1l + fcol);
          const int r0 = wave*4;
          for (int j = 0; j < 4; ++j)
            for (int c = 0; c < 4; ++c)
              Bs[r0+j][lane*4+c] = fmaxf(acc1[j][c] + bv[c], 0.f);
          __syncthreads();
          float acc2[4][4] = {};
          mm32s(Bs, Ws, W2l + (long)(y*256)*D, D, acc2);
          for (int j = 0; j < 4; ++j) {
            long row = row0 + r0 + j;
            cst2(&p.fp[((long)y*NMAX + row)*D + lane*4],     acc2[j][0], acc2[j][1]);
            cst2(&p.fp[((long)y*NMAX + row)*D + lane*4 + 2], acc2[j][2], acc2[j][3]);
          }
          __syncthreads();
        }
      }
      gbar(flags, ++ep);

      // ---- AE (l<2): LN2-fused stage + qkv for layer l+1 (staged W) ----
      if (l + 1 < NL) {
        const float* b2l = p.b2 + l*D;
        const float* g2l = p.g2 + l*D; const float* be2l = p.be2 + l*D;
        const float* Wl = p.Wqkv + (long)(l+1)*D*768;
        const float* bl = p.bqkv + (long)(l+1)*768;
        for (int t = wgid; t < 6*S; t += NWG) {
          int tt = t % (2*S), cp = t / (2*S);
          long row0 = (long)tt*TROWS;
          stageLN(As, p.xln1, row0, p.fp, 8, (long)NMAX*D, b2l, g2l, be2l,
                  (cp == 0) ? p.xcur : nullptr);
          float acc[4][4] = {};
          int col = cp*256 + lane*4;
          mm32s(As, Ws, Wl + cp*256, 768, acc);
          float bv[4]; *(float4*)bv = *(const float4*)(bl + col);
          const int r0 = wave*4;
          for (int j = 0; j < 4; ++j) {
            long row = row0 + r0 + j;
            cst2(&p.qkvb[row*768 + col],     acc[j][0] + bv[0], acc[j][1] + bv[1]);
            cst2(&p.qkvb[row*768 + col + 2], acc[j][2] + bv[2], acc[j][3] + bv[3]);
          }
          __syncthreads();
        }
        gbar(flags, ++ep);
      }
    } // layers

    // ---- F: LN2-fused stage + logits (staged W, XCD-stable colt) ----
    {
      const float* b2l = p.b2 + (NL-1)*D;
      const float* g2l = p.g2 + (NL-1)*D; const float* be2l = p.be2 + (NL-1)*D;
      const int x = wgid & 7, slot = wgid >> 3;
      const int rowt = slot & 1, cq = slot >> 1;
      const int colt = cq*8 + x;
      if (cq < 15 && colt < NCOLT) {
        long row0 = (long)i*BATCH + rowt*TROWS;
        stageLN(As, p.xln1, row0, p.fp, 8, (long)NMAX*D, b2l, g2l, be2l, nullptr);
        int col = colt*256 + lane*4;
        int colL = col > VOC-4 ? VOC-4 : col;
        float acc[4][4] = {};
        mm32sc(As, Ws, p.W_out, colt, acc);
        float bv[4]; *(float4*)bv = *(const float4*)(p.b_out + colL);
        bool valid = (col < VOC);
        const int r0 = wave*4;
        for (int j = 0; j < 4; ++j) {
          int b = rowt*TROWS + r0 + j;
          float v4[4]; float lm = -1e30f;
          for (int c = 0; c < 4; ++c) v4[c] = acc[j][c] + bv[c];
          if (valid) {
            cst2(&p.logits[(long)b*VOC + col],     v4[0], v4[1]);
            cst2(&p.logits[(long)b*VOC + col + 2], v4[2], v4[3]);
            for (int c = 0; c < 4; ++c) lm = fmaxf(lm, v4[c]);
          }
          float m = wredmax(lm);
          float ls = 0.f;
          if (valid) for (int c = 0; c < 4; ++c) ls += expf(v4[c] - m);
          for (int off = 32; off; off >>= 1) ls += __shfl_down(ls, off);
          float av = -1e30f; int ai = VOC;
          if (valid) for (int c = 0; c < 4; ++c) if (v4[c] > av) { av = v4[c]; ai = col + c; }
          for (int off = 32; off; off >>= 1) {
            float av2 = __shfl_down(av, off); int ai2 = __shfl_down(ai, off);
            if (av2 > av || (av2 == av && ai2 < ai)) { av = av2; ai = ai2; }
          }
          if (lane == 0) {
            int pidx = colt*64 + b;
            cst(&p.pm[pidx], m); cst(&p.pd[pidx], ls);
            cst(&p.pv[pidx], av); csti(&p.pi[pidx], ai);
          }
        }
      }
    }
    gbar(flags, ++ep);

    // ---- G: per-b merge; outputs + next embed ----
    if (wgid < BATCH) {
      int b = wgid;
      float* Lm = sm; float* Ld = sm + 128; float* Lv = sm + 256;
      int* Li = (int*)(sm + 384); int* Lei = Li + 128;
      if (tid < NCOLT) {
        Lm[tid] = cld(&p.pm[tid*64 + b]);
        Ld[tid] = cld(&p.pd[tid*64 + b]);
        Lv[tid] = cld(&p.pv[tid*64 + b]);
        Li[tid] = cldi(&p.pi[tid*64 + b]);
      }
      __syncthreads();
      if (tid == 0) {
        float gmax = -1e30f;
        for (int t2 = 0; t2 < NCOLT; ++t2) gmax = fmaxf(gmax, Lm[t2]);
        float Ssum = 0.f;
        for (int t2 = 0; t2 < NCOLT; ++t2) Ssum += Ld[t2] * expf(Lm[t2] - gmax);
        float bvv = -1e30f; int bi = VOC;
        for (int t2 = 0; t2 < NCOLT; ++t2)
          if (Lv[t2] > bvv || (Lv[t2] == bvv && Li[t2] < bi)) { bvv = Lv[t2]; bi = Li[t2]; }
        int run = 1;
        for (int j = 1; j <= i; ++j) if (p.target[b*BPTT + j] == 2) run = 0;
        float p2 = expf(cld(&p.logits[(long)b*VOC + 2]) - gmax) / Ssum;
        p.out_eos[b*BPTT + i] = p2;
        p.out_words[b*BPTT + i] = run ? (float)bi : 0.f;
        cst(&p.gS[b*2], gmax);
        cst(&p.gS[b*2+1], Ssum);
        csti(&p.maskS[b], run);
        Lei[0] = bi;
      }
      __syncthreads();
      if (i + 1 < BPTT && tid < 128) {
        int ei = Lei[0];
        int c2 = tid*2;
        cst2(&p.embeds[((long)(i+1)*BATCH + b)*D + c2],
             p.emb_table[(long)ei*D + c2], p.emb_table[(long)ei*D + c2 + 1]);
      }
    }
    gbar(flags, ++ep);
  } // steps

  // ---- final H: out_probs update for step 19 ----
  if (wgid < NCOLT) {
    float* gm = sm; float* ss = sm + 64; int* mk = (int*)(sm + 128);
    if (tid < 64) {
      gm[tid] = cld(&p.gS[tid*2]); ss[tid] = cld(&p.gS[tid*2+1]);
      mk[tid] = cldi(&p.maskS[tid]);
    }
    __syncthreads();
    int cbase = wgid*256;
    for (int idx = tid; idx < BATCH*128; idx += NTHR) {
      int b = idx >> 7, c = cbase + (idx & 127)*2;
      if (c < VOC && mk[b]) {
        float2 l = cld2(&p.logits[(long)b*VOC + c]);
        float pr0 = expf(l.x - gm[b]) / ss[b];
        float pr1 = expf(l.y - gm[b]) / ss[b];
        float* op = &p.out_probs[(long)b*VOC + c];
        op[0] = fmaxf(op[0], pr0);
        op[1] = fmaxf(op[1], pr1);
      }
    }
  }
}

// ---------------- host ----------------
extern "C" void kernel_launch(void* const* d_in, const int* in_sizes, int n_in,
                              void* d_out, int out_size, void* d_ws, size_t ws_size,
                              hipStream_t stream) {
  Params P;
  P.image_feats = (const float*)d_in[0];
  P.target      = (const int*)  d_in[1];
  P.emb_table   = (const float*)d_in[2];
  P.W_g2e       = (const float*)d_in[3];
  P.b_g2e       = (const float*)d_in[4];
  P.W_out       = (const float*)d_in[5];
  P.b_out       = (const float*)d_in[6];
  P.Wqkv        = (const float*)d_in[7];
  P.bqkv        = (const float*)d_in[8];
  P.Wo          = (const float*)d_in[9];
  P.bo          = (const float*)d_in[10];
  P.W1          = (const float*)d_in[11];
  P.b1          = (const float*)d_in[12];
  P.W2          = (const float*)d_in[13];
  P.b2          = (const float*)d_in[14];
  P.g1          = (const float*)d_in[15];
  P.be1         = (const float*)d_in[16];
  P.g2          = (const float*)d_in[17];
  P.be2         = (const float*)d_in[18];

  float* out_probs = (float*)d_out;
  P.out_probs = out_probs;
  P.out_words = out_probs + (long)BATCH*VOC;
  P.out_eos   = P.out_words + BATCH*BPTT;

  char* ws = (char*)d_ws;
  P.embeds = (float*)ws;  ws += sizeof(float)*(long)NMAX*D;
  P.xcur   = (float*)ws;  ws += sizeof(float)*(long)NMAX*D;
  P.xln1   = (float*)ws;  ws += sizeof(float)*(long)NMAX*D;
  P.qkvb0  = (float*)ws;  ws += sizeof(float)*(long)NMAX*3*D;
  P.qkvb   = (float*)ws;  ws += sizeof(float)*(long)NMAX*3*D;
  P.pp     = (float*)ws;  ws += sizeof(float)*(long)4*NMAX*D;
  P.fp     = (float*)ws;  ws += sizeof(float)*(long)8*NMAX*D;
  P.logits = (float*)ws;  ws += sizeof(float)*(long)BATCH*VOC;
  P.pm     = (float*)ws;  ws += sizeof(float)*NCOLT*64;
  P.pd     = (float*)ws;  ws += sizeof(float)*NCOLT*64;
  P.pv     = (float*)ws;  ws += sizeof(float)*NCOLT*64;
  P.gS     = (float*)ws;  ws += sizeof(float)*128;
  P.pi     = (int*)ws;    ws += sizeof(int)*NCOLT*64;
  P.maskS  = (int*)ws;    ws += sizeof(int)*64;
  P.flags  = (unsigned*)ws; ws += sizeof(unsigned)*(NWG*32 + 32); // +release line

  static bool inited = false;
  if (!inited) {
    hipFuncSetAttribute((const void*)mega,
                        hipFuncAttributeMaxDynamicSharedMemorySize, 98304);
    inited = true;
  }

  hipMemsetAsync(P.flags, 0, sizeof(unsigned)*(NWG*32 + 32), stream);
  void* args[] = { &P };
  hipError_t err = hipLaunchCooperativeKernel((void*)mega, dim3(NWG), dim3(NTHR),
                                              args, 98304, stream);
  if (err != hipSuccess) {
    // 256 blocks x 96KB LDS = 1 block/CU on 256 CUs: co-resident by capacity.
    hipLaunchKernelGGL(mega, dim3(NWG), dim3(NTHR), 98304, stream, P);
  }
}